// Round 8
// baseline (223.134 us; speedup 1.0000x reference)
//
#include <hip/hip_runtime.h>
#include <hip/hip_bf16.h>

#define BATCH 4
#define CH 256
#define CRD 32
#define NN 4096

typedef __bf16 bf16x8 __attribute__((ext_vector_type(8)));
typedef float floatx4 __attribute__((ext_vector_type(4)));
typedef float floatx16 __attribute__((ext_vector_type(16)));
typedef unsigned short ushort4v __attribute__((ext_vector_type(4)));
typedef unsigned short ushort8v __attribute__((ext_vector_type(8)));

static __device__ __forceinline__ unsigned short f2bf(float f) {
    unsigned int u = __float_as_uint(f);
    u += 0x7fff + ((u >> 16) & 1);           // RNE
    return (unsigned short)(u >> 16);
}
static __device__ __forceinline__ float bf2f(unsigned short h) {
    return __uint_as_float((unsigned int)h << 16);
}

// ---------------------------------------------------------------------------
// Fragment layout conventions (32x32x16 bf16 MFMA), verified R2-R7:
//   A[m][k]: lane l holds m = l&31, k = (l>>5)*8 + j
//   B[k][n]: lane l holds n = l&31, k = (l>>5)*8 + j
//   D      : lane l holds col = l&31, row = (r&3) + 8*(r>>2) + 4*(l>>5)
// Frag-major storage: addr = (tile*64 + (d32&31) + 32*((d16>>3)&1))*8 + (d16&7)
// => both A-frag and B-frag reads are lane-linear b128 loads.
// ---------------------------------------------------------------------------

// ---------------------------------------------------------------------------
// K0: weight prep. What: [mb 0..9][kblk 0..15] A-frag-major QKV weights
// (mb0 = Wq pre-scaled, mb1 = Wk, mb2-9 = Wv). WobF: same for Wo.
// ---------------------------------------------------------------------------
__global__ __launch_bounds__(256) void wconv_kernel(
    const float* __restrict__ Wq, const float* __restrict__ Wk,
    const float* __restrict__ Wv, const float* __restrict__ Wo,
    unsigned short* __restrict__ What, unsigned short* __restrict__ WobF)
{
    const int o = blockIdx.x;
    const int t = threadIdx.x;   // input channel c
    float scale = 1.0f;
    const float* src;
    if (o < 32)      { src = Wq + o * 256; scale = 0.17677669529663687f; }
    else if (o < 64) { src = Wk + (o - 32) * 256; }
    else             { src = Wv + (o - 64) * 256; }
    const int mb = o >> 5;
    const size_t idx = ((size_t)(mb * 16 + (t >> 4)) * 64
                        + (o & 31) + 32 * ((t >> 3) & 1)) * 8 + (t & 7);
    What[idx] = f2bf(src[t] * scale);
    if (o < 256) {
        const size_t i2 = ((size_t)((o >> 5) * 16 + (t >> 4)) * 64
                           + (o & 31) + 32 * ((t >> 3) & 1)) * 8 + (t & 7);
        WobF[i2] = f2bf(Wo[o * 256 + t]);
    }
}

// ---------------------------------------------------------------------------
// K1: QKV as MFMA GEMM. grid (128 n-tiles of 32, 4 b), block 256 (4 waves).
// Staging: thread loads 4 coalesced floats, writes one ds_write_b64.
// Outputs: qh/kh frag-major [b][nt][kblk 2][64][8]; vh [b][cblk 8][kf 256][64][8].
// ---------------------------------------------------------------------------
__global__ __launch_bounds__(256, 2) void qkv_kernel(
    const float* __restrict__ x, const unsigned short* __restrict__ What,
    unsigned short* __restrict__ qh, unsigned short* __restrict__ kh,
    unsigned short* __restrict__ vh)
{
    __shared__ unsigned short xf[16 * 512];   // 16 KB, frag-major x tile

    const int t = threadIdx.x;
    const int w = t >> 6;
    const int l = t & 63;
    const int l31 = l & 31;
    const int h = l >> 5;
    const int nt = blockIdx.x, b = blockIdx.y;
    const int n0 = nt * 32;

    // ---- stage: thread (n = t&31, cq = t>>5); per pass 4 c-rows -> b64 ----
    {
        const float* xb = x + (size_t)(b * CH) * NN + n0;
        const int n = t & 31;
        const int cq = t >> 5;           // 0..7
        #pragma unroll
        for (int p = 0; p < 8; ++p) {
            int c = p * 32 + cq * 4;
            float v0 = xb[(size_t)(c + 0) * NN + n];
            float v1 = xb[(size_t)(c + 1) * NN + n];
            float v2 = xb[(size_t)(c + 2) * NN + n];
            float v3 = xb[(size_t)(c + 3) * NN + n];
            ushort4v u4;
            u4[0] = f2bf(v0); u4[1] = f2bf(v1); u4[2] = f2bf(v2); u4[3] = f2bf(v3);
            int addr = ((2 * p + (cq >> 2)) * 64 + n + 32 * ((cq >> 1) & 1)) * 8
                       + 4 * (cq & 1);
            *(ushort4v*)&xf[addr] = u4;
        }
    }
    __syncthreads();

    const int mb0 = w, mb1 = w + 4, mb2 = w + 8;   // mb2 valid only for w<2
    floatx16 acc0, acc1, acc2;
    #pragma unroll
    for (int i = 0; i < 16; ++i) { acc0[i] = 0.f; acc1[i] = 0.f; acc2[i] = 0.f; }

    for (int kblk = 0; kblk < 16; ++kblk) {
        bf16x8 bf = *(const bf16x8*)&xf[kblk * 512 + l * 8];
        bf16x8 a0 = *(const bf16x8*)(What + ((size_t)(mb0 * 16 + kblk) * 64 + l) * 8);
        bf16x8 a1 = *(const bf16x8*)(What + ((size_t)(mb1 * 16 + kblk) * 64 + l) * 8);
        acc0 = __builtin_amdgcn_mfma_f32_32x32x16_bf16(a0, bf, acc0, 0, 0, 0);
        acc1 = __builtin_amdgcn_mfma_f32_32x32x16_bf16(a1, bf, acc1, 0, 0, 0);
        if (w < 2) {
            bf16x8 a2 = *(const bf16x8*)(What + ((size_t)(mb2 * 16 + kblk) * 64 + l) * 8);
            acc2 = __builtin_amdgcn_mfma_f32_32x32x16_bf16(a2, bf, acc2, 0, 0, 0);
        }
    }

    // q/k: rows=c(dim16), cols=n(dim32); r-quads are contiguous in c&7 -> ushort4
    auto store_qk = [&](unsigned short* dst, const floatx16& a) {
        size_t base = (size_t)(b * 128 + nt) * 1024;
        #pragma unroll
        for (int rg = 0; rg < 4; ++rg) {
            ushort4v u4;
            #pragma unroll
            for (int i = 0; i < 4; ++i) u4[i] = f2bf(a[rg * 4 + i]);
            size_t idx = base + (size_t)(rg >> 1) * 512
                         + (size_t)(l31 + 32 * (rg & 1)) * 8 + 4 * h;
            *(ushort4v*)(dst + idx) = u4;
        }
    };
    // v: rows=c(dim32), cols=key(dim16); scalar stores (elem fixed per lane)
    auto store_v = [&](int cblk, const floatx16& a) {
        size_t base = (((size_t)b * 8 + cblk) * 256 + nt * 2 + (l31 >> 4)) * 512
                      + 32 * ((l31 >> 3) & 1) * 8 + (l31 & 7);
        #pragma unroll
        for (int r = 0; r < 16; ++r) {
            int rowo = (r & 3) + 8 * (r >> 2) + 4 * h;
            vh[base + rowo * 8] = f2bf(a[r]);
        }
    };

    if (w == 0)      store_qk(qh, acc0);
    else if (w == 1) store_qk(kh, acc0);
    else             store_v(w - 2, acc0);
    store_v(w + 2, acc1);
    if (w < 2) store_v(w + 6, acc2);
}

// ---------------------------------------------------------------------------
// K2: flash attention, key-split 4 for occupancy (8 blocks/CU target).
// grid (128 q-tiles of 32, 4 key-splits, 4 b), block 256 (4 waves).
// Wave w: score key-slice [32w,+32); PV channels cblk {2w, 2w+1}.
// Writes UNNORMALIZED bf16 O-partials (K3-B-frag-major per (b,g,ks)) + (m,l).
// ---------------------------------------------------------------------------
__global__ __launch_bounds__(256, 8) void attn_kernel(
    const unsigned short* __restrict__ qh, const unsigned short* __restrict__ kh,
    const unsigned short* __restrict__ vh, unsigned short* __restrict__ Opart,
    float* __restrict__ ml)
{
    __shared__ unsigned short p_lds[8 * 64 * 8];   // 8 KB, frag-major P
    __shared__ float pmax_s[4][32];
    __shared__ float psum_s[4][32];

    const int t = threadIdx.x;
    const int w = t >> 6;
    const int l = t & 63;
    const int l31 = l & 31;
    const int h = l >> 5;
    const int g = blockIdx.x, ks = blockIdx.y, b = blockIdx.z;

    const unsigned short* qB = qh + (size_t)(b * 128 + g) * 1024;
    const unsigned short* kB = kh + (size_t)b * 128 * 1024;
    const unsigned short* vB = vh + (size_t)b * 8 * 256 * 512;

    // resident Q B-frags
    bf16x8 qf0 = *(const bf16x8*)(qB + l * 8);
    bf16x8 qf1 = *(const bf16x8*)(qB + 512 + l * 8);

    // prefetch K A-frags for iter 0 (key-tile = ks*32 + it*4 + w)
    bf16x8 kf0 = *(const bf16x8*)(kB + (size_t)(ks * 32 + w) * 1024 + l * 8);
    bf16x8 kf1 = *(const bf16x8*)(kB + (size_t)(ks * 32 + w) * 1024 + 512 + l * 8);

    float m_run = -1e30f, l_run = 0.f;
    floatx16 acc0, acc1;
    #pragma unroll
    for (int i = 0; i < 16; ++i) { acc0[i] = 0.f; acc1[i] = 0.f; }

    for (int it = 0; it < 8; ++it) {
        // ---- phase 1: scores S[32k][32q] for this wave's key slice ----
        floatx16 sacc;
        #pragma unroll
        for (int i = 0; i < 16; ++i) sacc[i] = 0.f;
        sacc = __builtin_amdgcn_mfma_f32_32x32x16_bf16(kf0, qf0, sacc, 0, 0, 0);
        sacc = __builtin_amdgcn_mfma_f32_32x32x16_bf16(kf1, qf1, sacc, 0, 0, 0);

        float pm = sacc[0];
        #pragma unroll
        for (int r = 1; r < 16; ++r) pm = fmaxf(pm, sacc[r]);
        pm = fmaxf(pm, __shfl_xor(pm, 32));
        if (h == 0) pmax_s[w][l31] = pm;
        __syncthreads();   // A: pmax visible; prev-iter p_lds reads done

        // ---- phase 2: online softmax, P -> LDS, prefetch next K ----
        float mnew = fmaxf(fmaxf(pmax_s[0][l31], pmax_s[1][l31]),
                           fmaxf(pmax_s[2][l31], pmax_s[3][l31]));
        mnew = fmaxf(m_run, mnew);
        float alpha = __expf(m_run - mnew);
        m_run = mnew;
        float pv[16];
        float psum = 0.f;
        #pragma unroll
        for (int r = 0; r < 16; ++r) {
            pv[r] = __expf(sacc[r] - mnew);
            psum += pv[r];
        }
        psum += __shfl_xor(psum, 32);
        if (h == 0) psum_s[w][l31] = psum;
        #pragma unroll
        for (int rg = 0; rg < 4; ++rg) {
            ushort4v pk;
            #pragma unroll
            for (int i = 0; i < 4; ++i) pk[i] = f2bf(pv[rg * 4 + i]);
            int idx = ((2 * w + (rg >> 1)) * 64 + l31 + 32 * (rg & 1)) * 8 + 4 * h;
            *(ushort4v*)&p_lds[idx] = pk;
        }
        if (it < 7) {
            const unsigned short* kn = kB + (size_t)(ks * 32 + (it + 1) * 4 + w) * 1024;
            kf0 = *(const bf16x8*)(kn + l * 8);
            kf1 = *(const bf16x8*)(kn + 512 + l * 8);
        }
        __syncthreads();   // B: p_lds + psum visible

        // ---- phase 3: rescale + PV from global V frags (depth-2 pipeline) ----
        float isum = (psum_s[0][l31] + psum_s[1][l31]) +
                     (psum_s[2][l31] + psum_s[3][l31]);
        l_run = l_run * alpha + isum;
        #pragma unroll
        for (int i = 0; i < 16; ++i) { acc0[i] *= alpha; acc1[i] *= alpha; }

        const unsigned short* v0b = vB + ((size_t)(2 * w) * 256 + (ks * 8 + it) * 8) * 512;
        const unsigned short* v1b = vB + ((size_t)(2 * w + 1) * 256 + (ks * 8 + it) * 8) * 512;
        bf16x8 va = *(const bf16x8*)(v0b + l * 8);
        bf16x8 vc = *(const bf16x8*)(v1b + l * 8);
        bf16x8 pf = *(const bf16x8*)&p_lds[l * 8];
        #pragma unroll
        for (int s = 0; s < 8; ++s) {
            bf16x8 va_n, vc_n, pf_n;
            if (s < 7) {
                va_n = *(const bf16x8*)(v0b + (s + 1) * 512 + l * 8);
                vc_n = *(const bf16x8*)(v1b + (s + 1) * 512 + l * 8);
                pf_n = *(const bf16x8*)&p_lds[((s + 1) * 64 + l) * 8];
            }
            acc0 = __builtin_amdgcn_mfma_f32_32x32x16_bf16(va, pf, acc0, 0, 0, 0);
            acc1 = __builtin_amdgcn_mfma_f32_32x32x16_bf16(vc, pf, acc1, 0, 0, 0);
            va = va_n; vc = vc_n; pf = pf_n;
        }
    }

    // ---- epilogue: write unnormalized frag-major bf16 O-partial + (m,l) ----
    unsigned short* op = Opart + ((size_t)((b * 128 + g) * 4 + ks)) * 8192;
    #pragma unroll
    for (int ct = 0; ct < 2; ++ct) {
        const floatx16& a = ct ? acc1 : acc0;
        #pragma unroll
        for (int rg = 0; rg < 4; ++rg) {
            ushort4v pk;
            #pragma unroll
            for (int i = 0; i < 4; ++i) pk[i] = f2bf(a[rg * 4 + i]);
            int sP = 4 * w + 2 * ct + (rg >> 1);
            size_t idx = ((size_t)sP * 64 + l31 + 32 * (rg & 1)) * 8 + 4 * h;
            *(ushort4v*)(op + idx) = pk;
        }
    }
    if (w == 0 && h == 0) {
        size_t mb = ((size_t)(b * 128 + g) * 4 + ks) * 64;
        ml[mb + l31] = m_run;
        ml[mb + 32 + l31] = l_run;
    }
}

// ---------------------------------------------------------------------------
// K3: combine 4 key-split partials (registers) + Wo GEMM + gamma*out + x.
// grid (128 q-tiles, 4 b), block 256 (4 waves; wave w -> o in [64w,64w+64)).
// ---------------------------------------------------------------------------
__global__ __launch_bounds__(256, 2) void out_kernel(
    const unsigned short* __restrict__ Opart, const float* __restrict__ ml,
    const unsigned short* __restrict__ WobF, const float* __restrict__ x,
    const float* __restrict__ gamma, float* __restrict__ out)
{
    const int t = threadIdx.x;
    const int w = t >> 6;
    const int l = t & 63;
    const int l31 = l & 31;
    const int h = l >> 5;
    const int qt = blockIdx.x, b = blockIdx.y;

    // per-lane combine weights for query q = l31
    const size_t slot = (size_t)(b * 128 + qt) * 4;
    float m0 = ml[(slot + 0) * 64 + l31], l0 = ml[(slot + 0) * 64 + 32 + l31];
    float m1 = ml[(slot + 1) * 64 + l31], l1 = ml[(slot + 1) * 64 + 32 + l31];
    float m2 = ml[(slot + 2) * 64 + l31], l2 = ml[(slot + 2) * 64 + 32 + l31];
    float m3 = ml[(slot + 3) * 64 + l31], l3 = ml[(slot + 3) * 64 + 32 + l31];
    float M = fmaxf(fmaxf(m0, m1), fmaxf(m2, m3));
    float e0 = __expf(m0 - M), e1 = __expf(m1 - M);
    float e2 = __expf(m2 - M), e3 = __expf(m3 - M);
    float Lc = l0 * e0 + l1 * e1 + l2 * e2 + l3 * e3;
    float w0 = e0 / Lc, w1 = e1 / Lc, w2 = e2 / Lc, w3 = e3 / Lc;

    const unsigned short* o0 = Opart + (slot + 0) * 8192;
    const unsigned short* o1 = Opart + (slot + 1) * 8192;
    const unsigned short* o2 = Opart + (slot + 2) * 8192;
    const unsigned short* o3 = Opart + (slot + 3) * 8192;

    floatx16 acc[2];
    #pragma unroll
    for (int m = 0; m < 2; ++m)
        #pragma unroll
        for (int i = 0; i < 16; ++i) acc[m][i] = 0.f;

    for (int s = 0; s < 16; ++s) {
        ushort8v f0 = *(const ushort8v*)(o0 + (s * 64 + l) * 8);
        ushort8v f1 = *(const ushort8v*)(o1 + (s * 64 + l) * 8);
        ushort8v f2 = *(const ushort8v*)(o2 + (s * 64 + l) * 8);
        ushort8v f3 = *(const ushort8v*)(o3 + (s * 64 + l) * 8);
        ushort8v cmb;
        #pragma unroll
        for (int j = 0; j < 8; ++j)
            cmb[j] = f2bf(w0 * bf2f(f0[j]) + w1 * bf2f(f1[j])
                        + w2 * bf2f(f2[j]) + w3 * bf2f(f3[j]));
        bf16x8 bfr = *(bf16x8*)&cmb;
        #pragma unroll
        for (int m = 0; m < 2; ++m) {
            int mt = 2 * w + m;
            bf16x8 af = *(const bf16x8*)(WobF + ((size_t)(mt * 16 + s) * 64 + l) * 8);
            acc[m] = __builtin_amdgcn_mfma_f32_32x32x16_bf16(af, bfr, acc[m], 0, 0, 0);
        }
    }

    const float gm = gamma[0];
    #pragma unroll
    for (int m = 0; m < 2; ++m)
        #pragma unroll
        for (int r = 0; r < 16; ++r) {
            int o = (2 * w + m) * 32 + (r & 3) + 8 * (r >> 2) + 4 * h;
            int n = qt * 32 + l31;
            size_t oi = ((size_t)(b * 256 + o)) * NN + n;
            out[oi] = gm * acc[m][r] + x[oi];
        }
}

// ---------------------------------------------------------------------------
extern "C" void kernel_launch(void* const* d_in, const int* in_sizes, int n_in,
                              void* d_out, int out_size, void* d_ws, size_t ws_size,
                              hipStream_t stream)
{
    const float* x     = (const float*)d_in[0];
    const float* Wq    = (const float*)d_in[1];
    const float* Wk    = (const float*)d_in[2];
    const float* Wv    = (const float*)d_in[3];
    const float* Wo    = (const float*)d_in[4];
    const float* gamma = (const float*)d_in[5];
    float* out = (float*)d_out;

    char* wsb = (char*)d_ws;
    unsigned short* qh    = (unsigned short*)(wsb);                          // 1 MB
    unsigned short* kh    = (unsigned short*)(wsb + (1u << 20));             // 1 MB
    unsigned short* vh    = (unsigned short*)(wsb + (2u << 20));             // 8 MB
    unsigned short* What  = (unsigned short*)(wsb + (10u << 20));            // 160 KB
    unsigned short* WobF  = (unsigned short*)(wsb + (10u << 20) + (256u << 10)); // 128 KB
    unsigned short* Opart = (unsigned short*)(wsb + (11u << 20));            // 33.6 MB
    float*          ml    = (float*)         (wsb + (45u << 20));            // 512 KB

    wconv_kernel<<<320, 256, 0, stream>>>(Wq, Wk, Wv, Wo, What, WobF);

    dim3 g1(128, BATCH);
    qkv_kernel<<<g1, 256, 0, stream>>>(x, What, qh, kh, vh);

    dim3 g2(128, 4, BATCH);
    attn_kernel<<<g2, 256, 0, stream>>>(qh, kh, vh, Opart, ml);

    dim3 g3(128, BATCH);
    out_kernel<<<g3, 256, 0, stream>>>(Opart, ml, WobF, x, gamma, out);
}

// Round 9
// 161.375 us; speedup vs baseline: 1.3827x; 1.3827x over previous
//
#include <hip/hip_runtime.h>
#include <hip/hip_bf16.h>

#define BATCH 4
#define CH 256
#define CRD 32
#define NN 4096

typedef __bf16 bf16x8 __attribute__((ext_vector_type(8)));
typedef float floatx4 __attribute__((ext_vector_type(4)));
typedef float floatx16 __attribute__((ext_vector_type(16)));
typedef unsigned short ushort4v __attribute__((ext_vector_type(4)));
typedef unsigned short ushort8v __attribute__((ext_vector_type(8)));

static __device__ __forceinline__ unsigned short f2bf(float f) {
    unsigned int u = __float_as_uint(f);
    u += 0x7fff + ((u >> 16) & 1);           // RNE
    return (unsigned short)(u >> 16);
}
static __device__ __forceinline__ float bf2f(unsigned short h) {
    return __uint_as_float((unsigned int)h << 16);
}

// ---------------------------------------------------------------------------
// Fragment layout conventions (32x32x16 bf16 MFMA), verified R2-R8:
//   A[m][k]: lane l holds m = l&31, k = (l>>5)*8 + j
//   B[k][n]: lane l holds n = l&31, k = (l>>5)*8 + j
//   D      : lane l holds col = l&31, row = (r&3) + 8*(r>>2) + 4*(l>>5)
// Frag-major storage: addr = (tile*64 + (d32&31) + 32*((d16>>3)&1))*8 + (d16&7)
// => both A-frag and B-frag reads are lane-linear b128 loads.
//
// REGISTER-BUDGET RULE (paid for twice, R3 + R8): never use __launch_bounds__
// to *demand* occupancy. attn needs ~48 VGPRs; (256,4) caps at 128 (safe),
// and actual 48 already permits 8 blocks/CU. (256,8) forced 32 -> spills
// (FETCH 37->176 MB, WRITE 16->116 MB).
// ---------------------------------------------------------------------------

// ---------------------------------------------------------------------------
// K0: weight prep. What: [mb 0..9][kblk 0..15] A-frag-major QKV weights
// (mb0 = Wq pre-scaled, mb1 = Wk, mb2-9 = Wv). WobF: same for Wo.
// ---------------------------------------------------------------------------
__global__ __launch_bounds__(256) void wconv_kernel(
    const float* __restrict__ Wq, const float* __restrict__ Wk,
    const float* __restrict__ Wv, const float* __restrict__ Wo,
    unsigned short* __restrict__ What, unsigned short* __restrict__ WobF)
{
    const int o = blockIdx.x;
    const int t = threadIdx.x;   // input channel c
    float scale = 1.0f;
    const float* src;
    if (o < 32)      { src = Wq + o * 256; scale = 0.17677669529663687f; }
    else if (o < 64) { src = Wk + (o - 32) * 256; }
    else             { src = Wv + (o - 64) * 256; }
    const int mb = o >> 5;
    const size_t idx = ((size_t)(mb * 16 + (t >> 4)) * 64
                        + (o & 31) + 32 * ((t >> 3) & 1)) * 8 + (t & 7);
    What[idx] = f2bf(src[t] * scale);
    if (o < 256) {
        const size_t i2 = ((size_t)((o >> 5) * 16 + (t >> 4)) * 64
                           + (o & 31) + 32 * ((t >> 3) & 1)) * 8 + (t & 7);
        WobF[i2] = f2bf(Wo[o * 256 + t]);
    }
}

// ---------------------------------------------------------------------------
// K1: QKV as MFMA GEMM. grid (128 n-tiles of 32, 4 b), block 256 (4 waves).
// Staging: thread loads 4 coalesced floats, writes one ds_write_b64.
// Outputs: qh/kh frag-major [b][nt][kblk 2][64][8]; vh [b][cblk 8][kf 256][64][8].
// ---------------------------------------------------------------------------
__global__ __launch_bounds__(256, 2) void qkv_kernel(
    const float* __restrict__ x, const unsigned short* __restrict__ What,
    unsigned short* __restrict__ qh, unsigned short* __restrict__ kh,
    unsigned short* __restrict__ vh)
{
    __shared__ unsigned short xf[16 * 512];   // 16 KB, frag-major x tile

    const int t = threadIdx.x;
    const int w = t >> 6;
    const int l = t & 63;
    const int l31 = l & 31;
    const int h = l >> 5;
    const int nt = blockIdx.x, b = blockIdx.y;
    const int n0 = nt * 32;

    // ---- stage: thread (n = t&31, cq = t>>5); per pass 4 c-rows -> b64 ----
    {
        const float* xb = x + (size_t)(b * CH) * NN + n0;
        const int n = t & 31;
        const int cq = t >> 5;           // 0..7
        #pragma unroll
        for (int p = 0; p < 8; ++p) {
            int c = p * 32 + cq * 4;
            float v0 = xb[(size_t)(c + 0) * NN + n];
            float v1 = xb[(size_t)(c + 1) * NN + n];
            float v2 = xb[(size_t)(c + 2) * NN + n];
            float v3 = xb[(size_t)(c + 3) * NN + n];
            ushort4v u4;
            u4[0] = f2bf(v0); u4[1] = f2bf(v1); u4[2] = f2bf(v2); u4[3] = f2bf(v3);
            int addr = ((2 * p + (cq >> 2)) * 64 + n + 32 * ((cq >> 1) & 1)) * 8
                       + 4 * (cq & 1);
            *(ushort4v*)&xf[addr] = u4;
        }
    }
    __syncthreads();

    const int mb0 = w, mb1 = w + 4, mb2 = w + 8;   // mb2 valid only for w<2
    floatx16 acc0, acc1, acc2;
    #pragma unroll
    for (int i = 0; i < 16; ++i) { acc0[i] = 0.f; acc1[i] = 0.f; acc2[i] = 0.f; }

    for (int kblk = 0; kblk < 16; ++kblk) {
        bf16x8 bf = *(const bf16x8*)&xf[kblk * 512 + l * 8];
        bf16x8 a0 = *(const bf16x8*)(What + ((size_t)(mb0 * 16 + kblk) * 64 + l) * 8);
        bf16x8 a1 = *(const bf16x8*)(What + ((size_t)(mb1 * 16 + kblk) * 64 + l) * 8);
        acc0 = __builtin_amdgcn_mfma_f32_32x32x16_bf16(a0, bf, acc0, 0, 0, 0);
        acc1 = __builtin_amdgcn_mfma_f32_32x32x16_bf16(a1, bf, acc1, 0, 0, 0);
        if (w < 2) {
            bf16x8 a2 = *(const bf16x8*)(What + ((size_t)(mb2 * 16 + kblk) * 64 + l) * 8);
            acc2 = __builtin_amdgcn_mfma_f32_32x32x16_bf16(a2, bf, acc2, 0, 0, 0);
        }
    }

    // q/k: rows=c(dim16), cols=n(dim32); r-quads are contiguous in c&7 -> ushort4
    auto store_qk = [&](unsigned short* dst, const floatx16& a) {
        size_t base = (size_t)(b * 128 + nt) * 1024;
        #pragma unroll
        for (int rg = 0; rg < 4; ++rg) {
            ushort4v u4;
            #pragma unroll
            for (int i = 0; i < 4; ++i) u4[i] = f2bf(a[rg * 4 + i]);
            size_t idx = base + (size_t)(rg >> 1) * 512
                         + (size_t)(l31 + 32 * (rg & 1)) * 8 + 4 * h;
            *(ushort4v*)(dst + idx) = u4;
        }
    };
    // v: rows=c(dim32), cols=key(dim16); scalar stores (elem fixed per lane)
    auto store_v = [&](int cblk, const floatx16& a) {
        size_t base = (((size_t)b * 8 + cblk) * 256 + nt * 2 + (l31 >> 4)) * 512
                      + 32 * ((l31 >> 3) & 1) * 8 + (l31 & 7);
        #pragma unroll
        for (int r = 0; r < 16; ++r) {
            int rowo = (r & 3) + 8 * (r >> 2) + 4 * h;
            vh[base + rowo * 8] = f2bf(a[r]);
        }
    };

    if (w == 0)      store_qk(qh, acc0);
    else if (w == 1) store_qk(kh, acc0);
    else             store_v(w - 2, acc0);
    store_v(w + 2, acc1);
    if (w < 2) store_v(w + 6, acc2);
}

// ---------------------------------------------------------------------------
// K2: flash attention, key-split 4; occupancy comes from ACTUAL VGPR=48
// (8 blocks/CU), launch_bounds stays (256,4) to avoid forced spills.
// grid (128 q-tiles of 32, 4 key-splits, 4 b), block 256 (4 waves).
// Wave w: score key-slice [32w,+32); PV channels cblk {2w, 2w+1}.
// Writes UNNORMALIZED bf16 O-partials (K3-B-frag-major per (b,g,ks)) + (m,l).
// ---------------------------------------------------------------------------
__global__ __launch_bounds__(256, 4) void attn_kernel(
    const unsigned short* __restrict__ qh, const unsigned short* __restrict__ kh,
    const unsigned short* __restrict__ vh, unsigned short* __restrict__ Opart,
    float* __restrict__ ml)
{
    __shared__ unsigned short p_lds[8 * 64 * 8];   // 8 KB, frag-major P
    __shared__ float pmax_s[4][32];
    __shared__ float psum_s[4][32];

    const int t = threadIdx.x;
    const int w = t >> 6;
    const int l = t & 63;
    const int l31 = l & 31;
    const int h = l >> 5;
    const int g = blockIdx.x, ks = blockIdx.y, b = blockIdx.z;

    const unsigned short* qB = qh + (size_t)(b * 128 + g) * 1024;
    const unsigned short* kB = kh + (size_t)b * 128 * 1024;
    const unsigned short* vB = vh + (size_t)b * 8 * 256 * 512;

    // resident Q B-frags
    bf16x8 qf0 = *(const bf16x8*)(qB + l * 8);
    bf16x8 qf1 = *(const bf16x8*)(qB + 512 + l * 8);

    // prefetch K A-frags for iter 0 (key-tile = ks*32 + it*4 + w)
    bf16x8 kf0 = *(const bf16x8*)(kB + (size_t)(ks * 32 + w) * 1024 + l * 8);
    bf16x8 kf1 = *(const bf16x8*)(kB + (size_t)(ks * 32 + w) * 1024 + 512 + l * 8);

    float m_run = -1e30f, l_run = 0.f;
    floatx16 acc0, acc1;
    #pragma unroll
    for (int i = 0; i < 16; ++i) { acc0[i] = 0.f; acc1[i] = 0.f; }

    for (int it = 0; it < 8; ++it) {
        // ---- phase 1: scores S[32k][32q] for this wave's key slice ----
        floatx16 sacc;
        #pragma unroll
        for (int i = 0; i < 16; ++i) sacc[i] = 0.f;
        sacc = __builtin_amdgcn_mfma_f32_32x32x16_bf16(kf0, qf0, sacc, 0, 0, 0);
        sacc = __builtin_amdgcn_mfma_f32_32x32x16_bf16(kf1, qf1, sacc, 0, 0, 0);

        float pm = sacc[0];
        #pragma unroll
        for (int r = 1; r < 16; ++r) pm = fmaxf(pm, sacc[r]);
        pm = fmaxf(pm, __shfl_xor(pm, 32));
        if (h == 0) pmax_s[w][l31] = pm;
        __syncthreads();   // A: pmax visible; prev-iter p_lds reads done

        // ---- phase 2: online softmax, P -> LDS, prefetch next K ----
        float mnew = fmaxf(fmaxf(pmax_s[0][l31], pmax_s[1][l31]),
                           fmaxf(pmax_s[2][l31], pmax_s[3][l31]));
        mnew = fmaxf(m_run, mnew);
        float alpha = __expf(m_run - mnew);
        m_run = mnew;
        float pv[16];
        float psum = 0.f;
        #pragma unroll
        for (int r = 0; r < 16; ++r) {
            pv[r] = __expf(sacc[r] - mnew);
            psum += pv[r];
        }
        psum += __shfl_xor(psum, 32);
        if (h == 0) psum_s[w][l31] = psum;
        #pragma unroll
        for (int rg = 0; rg < 4; ++rg) {
            ushort4v pk;
            #pragma unroll
            for (int i = 0; i < 4; ++i) pk[i] = f2bf(pv[rg * 4 + i]);
            int idx = ((2 * w + (rg >> 1)) * 64 + l31 + 32 * (rg & 1)) * 8 + 4 * h;
            *(ushort4v*)&p_lds[idx] = pk;
        }
        if (it < 7) {
            const unsigned short* kn = kB + (size_t)(ks * 32 + (it + 1) * 4 + w) * 1024;
            kf0 = *(const bf16x8*)(kn + l * 8);
            kf1 = *(const bf16x8*)(kn + 512 + l * 8);
        }
        __syncthreads();   // B: p_lds + psum visible

        // ---- phase 3: rescale + PV from global V frags (depth-2 pipeline) ----
        float isum = (psum_s[0][l31] + psum_s[1][l31]) +
                     (psum_s[2][l31] + psum_s[3][l31]);
        l_run = l_run * alpha + isum;
        #pragma unroll
        for (int i = 0; i < 16; ++i) { acc0[i] *= alpha; acc1[i] *= alpha; }

        const unsigned short* v0b = vB + ((size_t)(2 * w) * 256 + (ks * 8 + it) * 8) * 512;
        const unsigned short* v1b = vB + ((size_t)(2 * w + 1) * 256 + (ks * 8 + it) * 8) * 512;
        bf16x8 va = *(const bf16x8*)(v0b + l * 8);
        bf16x8 vc = *(const bf16x8*)(v1b + l * 8);
        bf16x8 pf = *(const bf16x8*)&p_lds[l * 8];
        #pragma unroll
        for (int s = 0; s < 8; ++s) {
            bf16x8 va_n, vc_n, pf_n;
            if (s < 7) {
                va_n = *(const bf16x8*)(v0b + (s + 1) * 512 + l * 8);
                vc_n = *(const bf16x8*)(v1b + (s + 1) * 512 + l * 8);
                pf_n = *(const bf16x8*)&p_lds[((s + 1) * 64 + l) * 8];
            }
            acc0 = __builtin_amdgcn_mfma_f32_32x32x16_bf16(va, pf, acc0, 0, 0, 0);
            acc1 = __builtin_amdgcn_mfma_f32_32x32x16_bf16(vc, pf, acc1, 0, 0, 0);
            va = va_n; vc = vc_n; pf = pf_n;
        }
    }

    // ---- epilogue: write unnormalized frag-major bf16 O-partial + (m,l) ----
    unsigned short* op = Opart + ((size_t)((b * 128 + g) * 4 + ks)) * 8192;
    #pragma unroll
    for (int ct = 0; ct < 2; ++ct) {
        const floatx16& a = ct ? acc1 : acc0;
        #pragma unroll
        for (int rg = 0; rg < 4; ++rg) {
            ushort4v pk;
            #pragma unroll
            for (int i = 0; i < 4; ++i) pk[i] = f2bf(a[rg * 4 + i]);
            int sP = 4 * w + 2 * ct + (rg >> 1);
            size_t idx = ((size_t)sP * 64 + l31 + 32 * (rg & 1)) * 8 + 4 * h;
            *(ushort4v*)(op + idx) = pk;
        }
    }
    if (w == 0 && h == 0) {
        size_t mb = ((size_t)(b * 128 + g) * 4 + ks) * 64;
        ml[mb + l31] = m_run;
        ml[mb + 32 + l31] = l_run;
    }
}

// ---------------------------------------------------------------------------
// K3: combine 4 key-split partials (registers) + Wo GEMM + gamma*out + x.
// grid (128 q-tiles, 4 b), block 256 (4 waves; wave w -> o in [64w,64w+64)).
// ---------------------------------------------------------------------------
__global__ __launch_bounds__(256, 2) void out_kernel(
    const unsigned short* __restrict__ Opart, const float* __restrict__ ml,
    const unsigned short* __restrict__ WobF, const float* __restrict__ x,
    const float* __restrict__ gamma, float* __restrict__ out)
{
    const int t = threadIdx.x;
    const int w = t >> 6;
    const int l = t & 63;
    const int l31 = l & 31;
    const int h = l >> 5;
    const int qt = blockIdx.x, b = blockIdx.y;

    // per-lane combine weights for query q = l31
    const size_t slot = (size_t)(b * 128 + qt) * 4;
    float m0 = ml[(slot + 0) * 64 + l31], l0 = ml[(slot + 0) * 64 + 32 + l31];
    float m1 = ml[(slot + 1) * 64 + l31], l1 = ml[(slot + 1) * 64 + 32 + l31];
    float m2 = ml[(slot + 2) * 64 + l31], l2 = ml[(slot + 2) * 64 + 32 + l31];
    float m3 = ml[(slot + 3) * 64 + l31], l3 = ml[(slot + 3) * 64 + 32 + l31];
    float M = fmaxf(fmaxf(m0, m1), fmaxf(m2, m3));
    float e0 = __expf(m0 - M), e1 = __expf(m1 - M);
    float e2 = __expf(m2 - M), e3 = __expf(m3 - M);
    float Lc = l0 * e0 + l1 * e1 + l2 * e2 + l3 * e3;
    float w0 = e0 / Lc, w1 = e1 / Lc, w2 = e2 / Lc, w3 = e3 / Lc;

    const unsigned short* o0 = Opart + (slot + 0) * 8192;
    const unsigned short* o1 = Opart + (slot + 1) * 8192;
    const unsigned short* o2 = Opart + (slot + 2) * 8192;
    const unsigned short* o3 = Opart + (slot + 3) * 8192;

    floatx16 acc[2];
    #pragma unroll
    for (int m = 0; m < 2; ++m)
        #pragma unroll
        for (int i = 0; i < 16; ++i) acc[m][i] = 0.f;

    for (int s = 0; s < 16; ++s) {
        ushort8v f0 = *(const ushort8v*)(o0 + (s * 64 + l) * 8);
        ushort8v f1 = *(const ushort8v*)(o1 + (s * 64 + l) * 8);
        ushort8v f2 = *(const ushort8v*)(o2 + (s * 64 + l) * 8);
        ushort8v f3 = *(const ushort8v*)(o3 + (s * 64 + l) * 8);
        ushort8v cmb;
        #pragma unroll
        for (int j = 0; j < 8; ++j)
            cmb[j] = f2bf(w0 * bf2f(f0[j]) + w1 * bf2f(f1[j])
                        + w2 * bf2f(f2[j]) + w3 * bf2f(f3[j]));
        bf16x8 bfr = *(bf16x8*)&cmb;
        #pragma unroll
        for (int m = 0; m < 2; ++m) {
            int mt = 2 * w + m;
            bf16x8 af = *(const bf16x8*)(WobF + ((size_t)(mt * 16 + s) * 64 + l) * 8);
            acc[m] = __builtin_amdgcn_mfma_f32_32x32x16_bf16(af, bfr, acc[m], 0, 0, 0);
        }
    }

    const float gm = gamma[0];
    #pragma unroll
    for (int m = 0; m < 2; ++m)
        #pragma unroll
        for (int r = 0; r < 16; ++r) {
            int o = (2 * w + m) * 32 + (r & 3) + 8 * (r >> 2) + 4 * h;
            int n = qt * 32 + l31;
            size_t oi = ((size_t)(b * 256 + o)) * NN + n;
            out[oi] = gm * acc[m][r] + x[oi];
        }
}

// ---------------------------------------------------------------------------
extern "C" void kernel_launch(void* const* d_in, const int* in_sizes, int n_in,
                              void* d_out, int out_size, void* d_ws, size_t ws_size,
                              hipStream_t stream)
{
    const float* x     = (const float*)d_in[0];
    const float* Wq    = (const float*)d_in[1];
    const float* Wk    = (const float*)d_in[2];
    const float* Wv    = (const float*)d_in[3];
    const float* Wo    = (const float*)d_in[4];
    const float* gamma = (const float*)d_in[5];
    float* out = (float*)d_out;

    char* wsb = (char*)d_ws;
    unsigned short* qh    = (unsigned short*)(wsb);                          // 1 MB
    unsigned short* kh    = (unsigned short*)(wsb + (1u << 20));             // 1 MB
    unsigned short* vh    = (unsigned short*)(wsb + (2u << 20));             // 8 MB
    unsigned short* What  = (unsigned short*)(wsb + (10u << 20));            // 160 KB
    unsigned short* WobF  = (unsigned short*)(wsb + (10u << 20) + (256u << 10)); // 128 KB
    unsigned short* Opart = (unsigned short*)(wsb + (11u << 20));            // 33.6 MB
    float*          ml    = (float*)         (wsb + (45u << 20));            // 512 KB

    wconv_kernel<<<320, 256, 0, stream>>>(Wq, Wk, Wv, Wo, What, WobF);

    dim3 g1(128, BATCH);
    qkv_kernel<<<g1, 256, 0, stream>>>(x, What, qh, kh, vh);

    dim3 g2(128, 4, BATCH);
    attn_kernel<<<g2, 256, 0, stream>>>(qh, kh, vh, Opart, ml);

    dim3 g3(128, BATCH);
    out_kernel<<<g3, 256, 0, stream>>>(Opart, ml, WobF, x, gamma, out);
}